// Round 6
// baseline (282.747 us; speedup 1.0000x reference)
//
#include <hip/hip_runtime.h>
#include <hip/hip_bf16.h>

#define DEV __device__ __forceinline__

typedef short bf16x8 __attribute__((ext_vector_type(8)));
typedef float f32x4 __attribute__((ext_vector_type(4)));
typedef unsigned int u32;

constexpr int BB = 2, SS = 2048, DD = 1024, HH = 16, DHD = 64;
constexpr int MM = BB * SS; // 4096
#define QSC 0.1803368801111f  /* 0.125 * log2(e): scores in log2 domain */

#if __has_builtin(__builtin_amdgcn_exp2f)
#define EXP2(x) __builtin_amdgcn_exp2f(x)
#else
#define EXP2(x) exp2f(x)
#endif

// round-half-up bf16; bias only at exact-half cases
DEV unsigned short f2bf(float f) {
    union { float f; unsigned int u; } v; v.f = f;
    return (unsigned short)((v.u + 0x8000u) >> 16);
}
// pack two f32 -> (bf16(b)<<16)|bf16(a) : add, add, v_perm = 3 instr
#if __has_builtin(__builtin_amdgcn_perm)
DEV u32 pk2bf(float a, float b) {
    union { float f; u32 u; } ua, ub; ua.f = a; ub.f = b;
    return __builtin_amdgcn_perm(ub.u + 0x8000u, ua.u + 0x8000u, 0x07060302u);
}
#else
DEV u32 pk2bf(float a, float b) {
    union { float f; u32 u; } ua, ub; ua.f = a; ub.f = b;
    return ((ua.u + 0x8000u) >> 16) | ((ub.u + 0x8000u) & 0xffff0000u);
}
#endif

DEV bf16x8 ld_bf16x8(const unsigned short* p) { return *(const bf16x8*)p; }

// async global->LDS, 16B per lane; lds dest = wave-uniform base + lane*16
DEV void gl16(const unsigned short* g, unsigned short* l) {
    __builtin_amdgcn_global_load_lds(
        (const __attribute__((address_space(1))) u32*)g,
        (__attribute__((address_space(3))) u32*)l, 16, 0, 0);
}

// ---- prep: xb = bf16(x) ----
__global__ void x2bf(const float* __restrict__ x, unsigned short* __restrict__ xb) {
    int i = blockIdx.x * 256 + threadIdx.x;
    float4 v = ((const float4*)x)[i];
    uint2 o;
    o.x = pk2bf(v.x, v.y);
    o.y = pk2bf(v.z, v.w);
    ((uint2*)xb)[i] = o;
}

// ---- prep: Wt[n][k] = bf16(W[k][n]) for all 4 weights ----
__global__ void transpose_w4(const float* __restrict__ W0, const float* __restrict__ W1,
                             const float* __restrict__ W2, const float* __restrict__ W3,
                             unsigned short* __restrict__ WtBase) {
    __shared__ float tile[32][33];
    const float* W = (blockIdx.z == 0) ? W0 : (blockIdx.z == 1) ? W1 : (blockIdx.z == 2) ? W2 : W3;
    unsigned short* Wt = WtBase + (size_t)blockIdx.z * DD * DD;
    int n0 = blockIdx.x * 32, k0 = blockIdx.y * 32;
    int tx = threadIdx.x, ty = threadIdx.y; // 32 x 8
    #pragma unroll
    for (int i = 0; i < 4; ++i)
        tile[ty + 8 * i][tx] = W[(size_t)(k0 + ty + 8 * i) * DD + n0 + tx];
    __syncthreads();
    #pragma unroll
    for (int i = 0; i < 4; ++i)
        Wt[(size_t)(n0 + ty + 8 * i) * DD + k0 + tx] = f2bf(tile[tx][ty + 8 * i]);
}

// ====================== QKV GEMM (128x128 tile, global_load_lds dbuf) ======================
__global__ __launch_bounds__(256) void qkv_gemm(
    const unsigned short* __restrict__ xb,
    const unsigned short* __restrict__ WtBase,
    const float* __restrict__ bq, const float* __restrict__ bk, const float* __restrict__ bv,
    unsigned short* __restrict__ Qb, unsigned short* __restrict__ Kb, unsigned short* __restrict__ Vt)
{
    __shared__ __align__(16) unsigned short Ald[2][128 * 32];
    __shared__ __align__(16) unsigned short Bld[2][128 * 32];

    const int z = blockIdx.z;
    const unsigned short* Wt = WtBase + (size_t)z * DD * DD;
    const float* bias = (z == 0) ? bq : (z == 1) ? bk : bv;

    const int m0g = blockIdx.y * 128;
    const int n0g = blockIdx.x * 128;
    const int wave = threadIdx.x >> 6, lane = threadIdx.x & 63;
    const int quad = lane >> 4, lcol = lane & 15;
    const int mb = (wave & 1) * 64, nb = (wave >> 1) * 64;

    f32x4 acc[4][4];
    #pragma unroll
    for (int i = 0; i < 4; ++i)
        #pragma unroll
        for (int j = 0; j < 4; ++j) acc[i][j] = (f32x4){0.f, 0.f, 0.f, 0.f};

    auto stage = [&](int ks, int bf) {
        #pragma unroll
        for (int i = 0; i < 4; ++i) {
            int j = wave * 4 + i;
            if (j < 8) { // A: xb rows m0g..m0g+127
                int bi = j * 64 + lane;
                int row = bi >> 2, p = (bi & 3) ^ (row & 3);
                gl16(xb + (size_t)(m0g + row) * DD + ks + p * 8, &Ald[bf][j * 512]);
            } else {     // B: Wt rows n0g..n0g+127
                int jj = j - 8;
                int bi = jj * 64 + lane;
                int row = bi >> 2, p = (bi & 3) ^ (row & 3);
                gl16(Wt + (size_t)(n0g + row) * DD + ks + p * 8, &Bld[bf][jj * 512]);
            }
        }
    };

    stage(0, 0);
    __syncthreads();

    for (int kk = 0; kk < 32; ++kk) {
        int bf = kk & 1;
        if (kk + 1 < 32) stage((kk + 1) * 32, (kk + 1) & 1);
        bf16x8 af[4], bfr[4];
        #pragma unroll
        for (int mt = 0; mt < 4; ++mt) {
            int row = mb + mt * 16 + lcol;
            af[mt] = ld_bf16x8(&Ald[bf][(row * 4 + (quad ^ (row & 3))) * 8]);
        }
        #pragma unroll
        for (int nt = 0; nt < 4; ++nt) {
            int row = nb + nt * 16 + lcol;
            bfr[nt] = ld_bf16x8(&Bld[bf][(row * 4 + (quad ^ (row & 3))) * 8]);
        }
        if (z < 2) { // transposed product: D[m=out_n][n=s]
            #pragma unroll
            for (int mt = 0; mt < 4; ++mt)
                #pragma unroll
                for (int nt = 0; nt < 4; ++nt)
                    acc[mt][nt] = __builtin_amdgcn_mfma_f32_16x16x32_bf16(bfr[nt], af[mt], acc[mt][nt], 0, 0, 0);
        } else {
            #pragma unroll
            for (int mt = 0; mt < 4; ++mt)
                #pragma unroll
                for (int nt = 0; nt < 4; ++nt)
                    acc[mt][nt] = __builtin_amdgcn_mfma_f32_16x16x32_bf16(af[mt], bfr[nt], acc[mt][nt], 0, 0, 0);
        }
        __syncthreads();
    }

    if (z < 2) {
        unsigned short* dst = (z == 0) ? Qb : Kb;
        const float sc = (z == 0) ? QSC : 1.0f;
        #pragma unroll
        for (int mt = 0; mt < 4; ++mt)
            #pragma unroll
            for (int nt = 0; nt < 4; ++nt) {
                int m = m0g + mb + mt * 16 + lcol;        // global row -> (b,s)
                int nbt = n0g + nb + nt * 16 + quad * 4;  // 4 consecutive out_n
                int b = m >> 11, s = m & (SS - 1);
                int h = nbt >> 6, dh0 = nbt & 63;
                float4 bv4 = *(const float4*)&bias[nbt];
                uint2 o;
                o.x = pk2bf((acc[mt][nt][0] + bv4.x) * sc, (acc[mt][nt][1] + bv4.y) * sc);
                o.y = pk2bf((acc[mt][nt][2] + bv4.z) * sc, (acc[mt][nt][3] + bv4.w) * sc);
                *(uint2*)&dst[(((size_t)b * HH + h) * SS + s) * DHD + dh0] = o;
            }
    } else {
        #pragma unroll
        for (int mt = 0; mt < 4; ++mt)
            #pragma unroll
            for (int nt = 0; nt < 4; ++nt) {
                int n = n0g + nb + nt * 16 + lcol;        // out_n
                int mbt = m0g + mb + mt * 16 + quad * 4;  // 4 consecutive global rows
                int h = n >> 6, dh = n & 63;
                int b = mbt >> 11, s0 = mbt & (SS - 1);
                float bvv = bias[n];
                uint2 o;
                o.x = pk2bf(acc[mt][nt][0] + bvv, acc[mt][nt][1] + bvv);
                o.y = pk2bf(acc[mt][nt][2] + bvv, acc[mt][nt][3] + bvv);
                *(uint2*)&Vt[(((size_t)b * HH + h) * DHD + dh) * SS + s0] = o;
            }
    }
}

// ====================== attention v6 ======================
// block = 2 waves; 32 q-rows shared, each wave owns 1024 keys (key-split).
// NO K/V LDS staging: fragments load directly global->VGPR (K/V are L2-resident
// per-XCD via block swizzle; R5 proved FETCH 12MB). LDS only for the wave-private
// P transpose (stride 72 = 16B-aligned b128, <=2-way banks) and the final O merge.
// Exact online-softmax merge between the 2 key-halves (wave-uniform m0, alpha).
__global__ __launch_bounds__(128) void attn(
    const unsigned short* __restrict__ Qb,
    const unsigned short* __restrict__ Kb,
    const unsigned short* __restrict__ Vt,
    unsigned short* __restrict__ Ob)
{
    __shared__ __align__(16) unsigned short tb[2][2][16 * 72]; // [wave][mt][row(lcol)][72]
    __shared__ __align__(16) float Obuf[32][68];
    __shared__ float lbuf[2][32];
    __shared__ float mbuf[2];

    const int g = blockIdx.y * gridDim.x + blockIdx.x;  // grid (64, 32)
    const int bh = (g & 7) * 4 + ((g >> 3) & 3);        // fixed g%8 (XCD) per bh
    const int qt = g >> 5;                              // 0..63
    const int b = bh >> 4, h = bh & (HH - 1);
    const unsigned short* Qbh = Qb + (size_t)bh * SS * DHD;
    const unsigned short* Kbh = Kb + (size_t)bh * SS * DHD;
    const unsigned short* Vbh = Vt + (size_t)bh * DHD * SS;

    const int wave = threadIdx.x >> 6, lane = threadIdx.x & 63;
    const int quad = lane >> 4, lcol = lane & 15;
    const int rowbase = qt * 32;
    const int key0 = wave * 1024;

    // Q B-frags (n = q-row, k = dh); 0.125*log2e folded into Q
    bf16x8 qf[2][2];
    #pragma unroll
    for (int mt = 0; mt < 2; ++mt)
        #pragma unroll
        for (int kf = 0; kf < 2; ++kf)
            qf[mt][kf] = ld_bf16x8(Qbh + (size_t)(rowbase + mt * 16 + lcol) * DHD + kf * 32 + quad * 8);

    // ---- wave-uniform m0 estimate from first 32 keys of this wave's range ----
    float m0 = -1e30f;
    #pragma unroll
    for (int kt = 0; kt < 2; ++kt) {
        const unsigned short* kp = Kbh + (size_t)(key0 + kt * 16 + lcol) * DHD + quad * 8;
        bf16x8 ka0 = ld_bf16x8(kp);
        bf16x8 ka1 = ld_bf16x8(kp + 32);
        #pragma unroll
        for (int mt = 0; mt < 2; ++mt) {
            f32x4 s = (f32x4){0.f, 0.f, 0.f, 0.f};
            s = __builtin_amdgcn_mfma_f32_16x16x32_bf16(ka0, qf[mt][0], s, 0, 0, 0);
            s = __builtin_amdgcn_mfma_f32_16x16x32_bf16(ka1, qf[mt][1], s, 0, 0, 0);
            #pragma unroll
            for (int r = 0; r < 4; ++r) m0 = fmaxf(m0, s[r]);
        }
    }
    #pragma unroll
    for (int msk = 1; msk < 64; msk <<= 1) m0 = fmaxf(m0, __shfl_xor(m0, msk, 64));
    const f32x4 minit = (f32x4){-m0, -m0, -m0, -m0};

    // ---- main loop: 16 chunks of 64 keys, all fragments direct from global ----
    f32x4 oacc[2][4];
    #pragma unroll
    for (int mt = 0; mt < 2; ++mt)
        #pragma unroll
        for (int nt = 0; nt < 4; ++nt) oacc[mt][nt] = (f32x4){0.f, 0.f, 0.f, 0.f};
    float ps[2] = {0.f, 0.f};

    for (int c = 0; c < 16; ++c) {
        const int kb = key0 + c * 64;

        // S^T = K.Q^T (C-init = -m0) -> exp2 -> packed b64 write into tbuf
        #pragma unroll
        for (int kt = 0; kt < 4; ++kt) {
            const unsigned short* kp = Kbh + (size_t)(kb + kt * 16 + lcol) * DHD + quad * 8;
            bf16x8 ka0 = ld_bf16x8(kp);
            bf16x8 ka1 = ld_bf16x8(kp + 32);
            #pragma unroll
            for (int mt = 0; mt < 2; ++mt) {
                f32x4 s = minit;
                s = __builtin_amdgcn_mfma_f32_16x16x32_bf16(ka0, qf[mt][0], s, 0, 0, 0);
                s = __builtin_amdgcn_mfma_f32_16x16x32_bf16(ka1, qf[mt][1], s, 0, 0, 0);
                float e0 = EXP2(s[0]), e1 = EXP2(s[1]);
                float e2 = EXP2(s[2]), e3 = EXP2(s[3]);
                ps[mt] += (e0 + e1) + (e2 + e3);
                *(uint2*)&tb[wave][mt][lcol * 72 + kt * 16 + quad * 4] =
                    make_uint2(pk2bf(e0, e1), pk2bf(e2, e3));
            }
        }

        // PV: A = P (from tbuf, wave-private, DS in-order), B = V direct global
        #pragma unroll
        for (int kf2 = 0; kf2 < 2; ++kf2) {
            bf16x8 vb[4];
            #pragma unroll
            for (int nt = 0; nt < 4; ++nt)
                vb[nt] = ld_bf16x8(Vbh + (size_t)(nt * 16 + lcol) * SS + kb + kf2 * 32 + quad * 8);
            #pragma unroll
            for (int mt = 0; mt < 2; ++mt) {
                bf16x8 pa = *(const bf16x8*)&tb[wave][mt][lcol * 72 + kf2 * 32 + quad * 8];
                #pragma unroll
                for (int nt = 0; nt < 4; ++nt)
                    oacc[mt][nt] = __builtin_amdgcn_mfma_f32_16x16x32_bf16(pa, vb[nt], oacc[mt][nt], 0, 0, 0);
            }
        }
    }

    // ---- row sums within wave ----
    #pragma unroll
    for (int mt = 0; mt < 2; ++mt) {
        ps[mt] += __shfl_xor(ps[mt], 16, 64);
        ps[mt] += __shfl_xor(ps[mt], 32, 64);
    }

    // ---- exact merge of the two key-halves ----
    if (lane == 0) mbuf[wave] = m0;
    __syncthreads();
    const float M = fmaxf(mbuf[0], mbuf[1]);
    const float alpha = EXP2(m0 - M);   // wave-uniform

    // lbuf[wave][q] = alpha * l_wave
    if (quad == 0) {
        #pragma unroll
        for (int mt = 0; mt < 2; ++mt)
            lbuf[wave][mt * 16 + lcol] = alpha * ps[mt]; // ps valid per-lane after xor-reduce
    }
    // Obuf: wave 0 writes, then wave 1 accumulates
    if (wave == 0) {
        #pragma unroll
        for (int mt = 0; mt < 2; ++mt)
            #pragma unroll
            for (int nt = 0; nt < 4; ++nt)
                #pragma unroll
                for (int r = 0; r < 4; ++r)
                    Obuf[mt * 16 + quad * 4 + r][nt * 16 + lcol] = alpha * oacc[mt][nt][r];
    }
    __syncthreads();
    if (wave == 1) {
        #pragma unroll
        for (int mt = 0; mt < 2; ++mt)
            #pragma unroll
            for (int nt = 0; nt < 4; ++nt)
                #pragma unroll
                for (int r = 0; r < 4; ++r)
                    Obuf[mt * 16 + quad * 4 + r][nt * 16 + lcol] += alpha * oacc[mt][nt][r];
    }
    __syncthreads();

    // ---- normalize + vectorized store: 128 threads x 16 bf16 (32B) each ----
    {
        const int t = threadIdx.x;
        const int row = t >> 2;            // 0..31
        const int dh0 = (t & 3) * 16;
        float inv = 1.0f / (lbuf[0][row] + lbuf[1][row]);
        const float* src = &Obuf[row][dh0];
        uint4 o0, o1;
        o0.x = pk2bf(src[0] * inv,  src[1] * inv);
        o0.y = pk2bf(src[2] * inv,  src[3] * inv);
        o0.z = pk2bf(src[4] * inv,  src[5] * inv);
        o0.w = pk2bf(src[6] * inv,  src[7] * inv);
        o1.x = pk2bf(src[8] * inv,  src[9] * inv);
        o1.y = pk2bf(src[10] * inv, src[11] * inv);
        o1.z = pk2bf(src[12] * inv, src[13] * inv);
        o1.w = pk2bf(src[14] * inv, src[15] * inv);
        size_t base = (((size_t)b * SS + rowbase + row) * HH + h) * DHD + dh0;
        *(uint4*)&Ob[base] = o0;
        *(uint4*)&Ob[base + 8] = o1;
    }
}

// ====================== output GEMM (64x128 tile, 512 blocks) ======================
__global__ __launch_bounds__(256) void out_gemm(
    const unsigned short* __restrict__ Ob,
    const unsigned short* __restrict__ Wto,
    const float* __restrict__ bo,
    float* __restrict__ out)
{
    __shared__ __align__(16) unsigned short Ald[2][64 * 32];
    __shared__ __align__(16) unsigned short Bld[2][128 * 32];

    const int m0g = blockIdx.y * 64;
    const int n0g = blockIdx.x * 128;
    const int wave = threadIdx.x >> 6, lane = threadIdx.x & 63;
    const int quad = lane >> 4, lcol = lane & 15;
    const int nb = wave * 32;

    f32x4 acc[4][2];
    #pragma unroll
    for (int i = 0; i < 4; ++i)
        #pragma unroll
        for (int j = 0; j < 2; ++j) acc[i][j] = (f32x4){0.f, 0.f, 0.f, 0.f};

    auto stage = [&](int ks, int bf) {
        #pragma unroll
        for (int i = 0; i < 3; ++i) {
            int j = wave * 3 + i;
            if (j < 4) { // A: Ob rows m0g..m0g+63
                int bi = j * 64 + lane;
                int row = bi >> 2, p = (bi & 3) ^ (row & 3);
                gl16(Ob + (size_t)(m0g + row) * DD + ks + p * 8, &Ald[bf][j * 512]);
            } else {     // B: Wto rows n0g..n0g+127
                int jj = j - 4;
                int bi = jj * 64 + lane;
                int row = bi >> 2, p = (bi & 3) ^ (row & 3);
                gl16(Wto + (size_t)(n0g + row) * DD + ks + p * 8, &Bld[bf][jj * 512]);
            }
        }
    };

    stage(0, 0);
    __syncthreads();

    for (int kk = 0; kk < 32; ++kk) {
        int bf = kk & 1;
        if (kk + 1 < 32) stage((kk + 1) * 32, (kk + 1) & 1);
        bf16x8 af[4], bfr[2];
        #pragma unroll
        for (int mt = 0; mt < 4; ++mt) {
            int row = mt * 16 + lcol;
            af[mt] = ld_bf16x8(&Ald[bf][(row * 4 + (quad ^ (row & 3))) * 8]);
        }
        #pragma unroll
        for (int nt = 0; nt < 2; ++nt) {
            int row = nb + nt * 16 + lcol;
            bfr[nt] = ld_bf16x8(&Bld[bf][(row * 4 + (quad ^ (row & 3))) * 8]);
        }
        #pragma unroll
        for (int mt = 0; mt < 4; ++mt)
            #pragma unroll
            for (int nt = 0; nt < 2; ++nt)
                acc[mt][nt] = __builtin_amdgcn_mfma_f32_16x16x32_bf16(af[mt], bfr[nt], acc[mt][nt], 0, 0, 0);
        __syncthreads();
    }

    #pragma unroll
    for (int mt = 0; mt < 4; ++mt)
        #pragma unroll
        for (int nt = 0; nt < 2; ++nt) {
            int n = n0g + nb + nt * 16 + lcol;
            float bv_ = bo[n];
            #pragma unroll
            for (int r = 0; r < 4; ++r) {
                int m = m0g + mt * 16 + quad * 4 + r;
                out[(size_t)m * DD + n] = acc[mt][nt][r] + bv_;
            }
        }
}

extern "C" void kernel_launch(void* const* d_in, const int* in_sizes, int n_in,
                              void* d_out, int out_size, void* d_ws, size_t ws_size,
                              hipStream_t stream)
{
    const float* x  = (const float*)d_in[0];
    const float* Wq = (const float*)d_in[1];
    const float* bq = (const float*)d_in[2];
    const float* Wk = (const float*)d_in[3];
    const float* bk = (const float*)d_in[4];
    const float* Wv = (const float*)d_in[5];
    const float* bv = (const float*)d_in[6];
    const float* Wo = (const float*)d_in[7];
    const float* bo = (const float*)d_in[8];
    float* out = (float*)d_out;

    unsigned short* ws = (unsigned short*)d_ws;
    unsigned short* Wt  = ws;                        // 4 * D*D (q,k,v,o)
    unsigned short* Wto = Wt + 3 * (size_t)DD * DD;
    unsigned short* Qb  = Wt + 4 * (size_t)DD * DD;  // M*D each
    unsigned short* Kb  = Qb + (size_t)MM * DD;
    unsigned short* Vt  = Kb + (size_t)MM * DD;
    unsigned short* xb  = Vt + (size_t)MM * DD;      // total 40 MB
    unsigned short* Ob  = xb;                        // alias: xb dead after qkv_gemm

    x2bf<<<MM * DD / 4 / 256, 256, 0, stream>>>(x, xb);
    transpose_w4<<<dim3(DD / 32, DD / 32, 4), dim3(32, 8), 0, stream>>>(Wq, Wk, Wv, Wo, Wt);

    qkv_gemm<<<dim3(DD / 128, MM / 128, 3), 256, 0, stream>>>(xb, Wt, bq, bk, bv, Qb, Kb, Vt);

    attn<<<dim3(64, 32), 128, 0, stream>>>(Qb, Kb, Vt, Ob);

    out_gemm<<<dim3(DD / 128, MM / 64), 256, 0, stream>>>(Ob, Wto, bo, out);
}

// Round 7
// 210.429 us; speedup vs baseline: 1.3437x; 1.3437x over previous
//
#include <hip/hip_runtime.h>
#include <hip/hip_bf16.h>

#define DEV __device__ __forceinline__

typedef short bf16x8 __attribute__((ext_vector_type(8)));
typedef float f32x4 __attribute__((ext_vector_type(4)));
typedef unsigned int u32;

constexpr int BB = 2, SS = 2048, DD = 1024, HH = 16, DHD = 64;
constexpr int MM = BB * SS; // 4096
#define QSC 0.1803368801111f  /* 0.125 * log2(e): scores in log2 domain */

#if __has_builtin(__builtin_amdgcn_exp2f)
#define EXP2(x) __builtin_amdgcn_exp2f(x)
#else
#define EXP2(x) exp2f(x)
#endif

// round-half-up bf16; bias only at exact-half cases
DEV unsigned short f2bf(float f) {
    union { float f; unsigned int u; } v; v.f = f;
    return (unsigned short)((v.u + 0x8000u) >> 16);
}
// pack two f32 -> (bf16(b)<<16)|bf16(a) : add, add, v_perm = 3 instr
#if __has_builtin(__builtin_amdgcn_perm)
DEV u32 pk2bf(float a, float b) {
    union { float f; u32 u; } ua, ub; ua.f = a; ub.f = b;
    return __builtin_amdgcn_perm(ub.u + 0x8000u, ua.u + 0x8000u, 0x07060302u);
}
#else
DEV u32 pk2bf(float a, float b) {
    union { float f; u32 u; } ua, ub; ua.f = a; ub.f = b;
    return ((ua.u + 0x8000u) >> 16) | ((ub.u + 0x8000u) & 0xffff0000u);
}
#endif

DEV bf16x8 ld_bf16x8(const unsigned short* p) { return *(const bf16x8*)p; }

// async global->LDS, 16B per lane; lds dest = wave-uniform base + lane*16
DEV void gl16(const unsigned short* g, unsigned short* l) {
    __builtin_amdgcn_global_load_lds(
        (const __attribute__((address_space(1))) u32*)g,
        (__attribute__((address_space(3))) u32*)l, 16, 0, 0);
}

// ---- prep (fused): blocks [0,4096) = x->bf16 ; [4096,8192) = W transposes ----
__global__ void prep(const float* __restrict__ x, unsigned short* __restrict__ xb,
                     const float* __restrict__ W0, const float* __restrict__ W1,
                     const float* __restrict__ W2, const float* __restrict__ W3,
                     unsigned short* __restrict__ WtBase) {
    __shared__ float tile[32][33];
    int blk = blockIdx.x;
    if (blk < 4096) {
        int i = blk * 256 + threadIdx.x;
        float4 v = ((const float4*)x)[i];
        uint2 o;
        o.x = pk2bf(v.x, v.y);
        o.y = pk2bf(v.z, v.w);
        ((uint2*)xb)[i] = o;
        return;
    }
    blk -= 4096;                 // 4 weights x 1024 tiles
    int wsel = blk >> 10;
    const float* W = (wsel == 0) ? W0 : (wsel == 1) ? W1 : (wsel == 2) ? W2 : W3;
    unsigned short* Wt = WtBase + (size_t)wsel * DD * DD;
    int t = blk & 1023;
    int n0 = (t & 31) * 32, k0 = (t >> 5) * 32;
    int tx = threadIdx.x & 31, ty = threadIdx.x >> 5; // 32 x 8
    #pragma unroll
    for (int i = 0; i < 4; ++i)
        tile[ty + 8 * i][tx] = W[(size_t)(k0 + ty + 8 * i) * DD + n0 + tx];
    __syncthreads();
    #pragma unroll
    for (int i = 0; i < 4; ++i)
        Wt[(size_t)(n0 + ty + 8 * i) * DD + k0 + tx] = f2bf(tile[tx][ty + 8 * i]);
}

// ====================== QKV GEMM (128x128 tile, global_load_lds dbuf) ======================
__global__ __launch_bounds__(256) void qkv_gemm(
    const unsigned short* __restrict__ xb,
    const unsigned short* __restrict__ WtBase,
    const float* __restrict__ bq, const float* __restrict__ bk, const float* __restrict__ bv,
    unsigned short* __restrict__ Qb, unsigned short* __restrict__ Kb, unsigned short* __restrict__ Vt)
{
    __shared__ __align__(16) unsigned short Ald[2][128 * 32];
    __shared__ __align__(16) unsigned short Bld[2][128 * 32];

    const int z = blockIdx.z;
    const unsigned short* Wt = WtBase + (size_t)z * DD * DD;
    const float* bias = (z == 0) ? bq : (z == 1) ? bk : bv;

    const int m0g = blockIdx.y * 128;
    const int n0g = blockIdx.x * 128;
    const int wave = threadIdx.x >> 6, lane = threadIdx.x & 63;
    const int quad = lane >> 4, lcol = lane & 15;
    const int mb = (wave & 1) * 64, nb = (wave >> 1) * 64;

    f32x4 acc[4][4];
    #pragma unroll
    for (int i = 0; i < 4; ++i)
        #pragma unroll
        for (int j = 0; j < 4; ++j) acc[i][j] = (f32x4){0.f, 0.f, 0.f, 0.f};

    auto stage = [&](int ks, int bf) {
        #pragma unroll
        for (int i = 0; i < 4; ++i) {
            int j = wave * 4 + i;
            if (j < 8) { // A: xb rows m0g..m0g+127
                int bi = j * 64 + lane;
                int row = bi >> 2, p = (bi & 3) ^ (row & 3);
                gl16(xb + (size_t)(m0g + row) * DD + ks + p * 8, &Ald[bf][j * 512]);
            } else {     // B: Wt rows n0g..n0g+127
                int jj = j - 8;
                int bi = jj * 64 + lane;
                int row = bi >> 2, p = (bi & 3) ^ (row & 3);
                gl16(Wt + (size_t)(n0g + row) * DD + ks + p * 8, &Bld[bf][jj * 512]);
            }
        }
    };

    stage(0, 0);
    __syncthreads();

    for (int kk = 0; kk < 32; ++kk) {
        int bf = kk & 1;
        if (kk + 1 < 32) stage((kk + 1) * 32, (kk + 1) & 1);
        bf16x8 af[4], bfr[4];
        #pragma unroll
        for (int mt = 0; mt < 4; ++mt) {
            int row = mb + mt * 16 + lcol;
            af[mt] = ld_bf16x8(&Ald[bf][(row * 4 + (quad ^ (row & 3))) * 8]);
        }
        #pragma unroll
        for (int nt = 0; nt < 4; ++nt) {
            int row = nb + nt * 16 + lcol;
            bfr[nt] = ld_bf16x8(&Bld[bf][(row * 4 + (quad ^ (row & 3))) * 8]);
        }
        if (z < 2) { // transposed product: D[m=out_n][n=s]
            #pragma unroll
            for (int mt = 0; mt < 4; ++mt)
                #pragma unroll
                for (int nt = 0; nt < 4; ++nt)
                    acc[mt][nt] = __builtin_amdgcn_mfma_f32_16x16x32_bf16(bfr[nt], af[mt], acc[mt][nt], 0, 0, 0);
        } else {
            #pragma unroll
            for (int mt = 0; mt < 4; ++mt)
                #pragma unroll
                for (int nt = 0; nt < 4; ++nt)
                    acc[mt][nt] = __builtin_amdgcn_mfma_f32_16x16x32_bf16(af[mt], bfr[nt], acc[mt][nt], 0, 0, 0);
        }
        __syncthreads();
    }

    if (z < 2) {
        unsigned short* dst = (z == 0) ? Qb : Kb;
        const float sc = (z == 0) ? QSC : 1.0f;
        #pragma unroll
        for (int mt = 0; mt < 4; ++mt)
            #pragma unroll
            for (int nt = 0; nt < 4; ++nt) {
                int m = m0g + mb + mt * 16 + lcol;        // global row -> (b,s)
                int nbt = n0g + nb + nt * 16 + quad * 4;  // 4 consecutive out_n
                int b = m >> 11, s = m & (SS - 1);
                int h = nbt >> 6, dh0 = nbt & 63;
                float4 bv4 = *(const float4*)&bias[nbt];
                uint2 o;
                o.x = pk2bf((acc[mt][nt][0] + bv4.x) * sc, (acc[mt][nt][1] + bv4.y) * sc);
                o.y = pk2bf((acc[mt][nt][2] + bv4.z) * sc, (acc[mt][nt][3] + bv4.w) * sc);
                *(uint2*)&dst[(((size_t)b * HH + h) * SS + s) * DHD + dh0] = o;
            }
    } else {
        #pragma unroll
        for (int mt = 0; mt < 4; ++mt)
            #pragma unroll
            for (int nt = 0; nt < 4; ++nt) {
                int n = n0g + nb + nt * 16 + lcol;        // out_n
                int mbt = m0g + mb + mt * 16 + quad * 4;  // 4 consecutive global rows
                int h = n >> 6, dh = n & 63;
                int b = mbt >> 11, s0 = mbt & (SS - 1);
                float bvv = bias[n];
                uint2 o;
                o.x = pk2bf(acc[mt][nt][0] + bvv, acc[mt][nt][1] + bvv);
                o.y = pk2bf(acc[mt][nt][2] + bvv, acc[mt][nt][3] + bvv);
                *(uint2*)&Vt[(((size_t)b * HH + h) * DHD + dh) * SS + s0] = o;
            }
    }
}

// ====================== attention v7 ======================
// block = 512 threads (8 waves), 128 q-rows; wave owns 16 rows over ALL 2048 keys.
// Grid 512 blocks, XCD-swizzled (R5: FETCH 12MB). K/V chunks (64 keys) staged via
// global_load_lds dbuf (R4 structure). 8 waves -> 4 waves/SIMD for latency cover.
// tbuf stride 68 shorts (R5: 0 bank conflicts). Scores in log2 domain; -m0 in C-init.
__global__ __launch_bounds__(512, 4) void attn(
    const unsigned short* __restrict__ Qb,
    const unsigned short* __restrict__ Kb,
    const unsigned short* __restrict__ Vt,
    unsigned short* __restrict__ Ob)
{
    __shared__ __align__(16) unsigned short Kld[2][64 * 64]; // keys x dh, swizzled blocks
    __shared__ __align__(16) unsigned short Vld[2][64 * 64]; // dh x keys, swizzled blocks
    __shared__ __align__(16) unsigned short tb[8][16 * 68];  // [wave][row(lcol)][key], stride 68

    const int g = blockIdx.y * gridDim.x + blockIdx.x;  // grid (16, 32) = 512
    const int bh = (g & 7) * 4 + ((g >> 3) & 3);        // fixed g%32 per bh -> fixed XCD
    const int qt = g >> 5;                               // 0..15
    const int b = bh >> 4, h = bh & (HH - 1);
    const unsigned short* Qbh = Qb + (size_t)bh * SS * DHD;
    const unsigned short* Kbh = Kb + (size_t)bh * SS * DHD;
    const unsigned short* Vbh = Vt + (size_t)bh * DHD * SS;

    const int wave = threadIdx.x >> 6, lane = threadIdx.x & 63;
    const int quad = lane >> 4, lcol = lane & 15;
    const int rowbase = qt * 128 + wave * 16;

    // Q B-frags (n = q-row, k = dh); 0.125*log2e folded into Q
    bf16x8 qf0 = ld_bf16x8(Qbh + (size_t)(rowbase + lcol) * DHD + quad * 8);
    bf16x8 qf1 = ld_bf16x8(Qbh + (size_t)(rowbase + lcol) * DHD + 32 + quad * 8);

    auto stage = [&](int c, int bf) {
        int kb = c * 64;
        #pragma unroll
        for (int i = 0; i < 2; ++i) {
            int j = wave * 2 + i;
            if (j < 8) { // K: rows = keys, 8 parts of dh
                int bi = j * 64 + lane;
                int r = bi >> 3, p = (bi & 7) ^ (r & 7);
                gl16(Kbh + (size_t)(kb + r) * DHD + p * 8, &Kld[bf][j * 512]);
            } else {     // V: rows = dh, 8 parts of keys
                int jj = j - 8;
                int bi = jj * 64 + lane;
                int dh = bi >> 3, p = (bi & 7) ^ (dh & 7);
                gl16(Vbh + (size_t)dh * SS + kb + p * 8, &Vld[bf][jj * 512]);
            }
        }
    };

    // ---- prologue: stage chunk 0, wave-uniform m0 estimate from it ----
    stage(0, 0);
    __syncthreads();

    float m0 = -1e30f;
    #pragma unroll
    for (int kt = 0; kt < 4; ++kt) {
        int r0 = kt * 16 + lcol;
        bf16x8 ka0 = ld_bf16x8(&Kld[0][(r0 * 8 + (quad ^ (r0 & 7))) * 8]);
        bf16x8 ka1 = ld_bf16x8(&Kld[0][(r0 * 8 + ((quad + 4) ^ (r0 & 7))) * 8]);
        f32x4 s = (f32x4){0.f, 0.f, 0.f, 0.f};
        s = __builtin_amdgcn_mfma_f32_16x16x32_bf16(ka0, qf0, s, 0, 0, 0);
        s = __builtin_amdgcn_mfma_f32_16x16x32_bf16(ka1, qf1, s, 0, 0, 0);
        #pragma unroll
        for (int r = 0; r < 4; ++r) m0 = fmaxf(m0, s[r]);
    }
    #pragma unroll
    for (int msk = 1; msk < 64; msk <<= 1) m0 = fmaxf(m0, __shfl_xor(m0, msk, 64));
    const f32x4 minit = (f32x4){-m0, -m0, -m0, -m0};

    // ---- main loop over 32 chunks of 64 keys ----
    f32x4 oacc[4];
    #pragma unroll
    for (int nt = 0; nt < 4; ++nt) oacc[nt] = (f32x4){0.f, 0.f, 0.f, 0.f};
    float ps = 0.f;

    for (int c = 0; c < 32; ++c) {
        int bf = c & 1;
        if (c + 1 < 32) stage(c + 1, (c + 1) & 1);

        // S^T = K.Q^T (C-init = -m0) -> exp2 -> packed b64 write into tbuf
        #pragma unroll
        for (int kt = 0; kt < 4; ++kt) {
            int r0 = kt * 16 + lcol;
            bf16x8 ka0 = ld_bf16x8(&Kld[bf][(r0 * 8 + (quad ^ (r0 & 7))) * 8]);
            bf16x8 ka1 = ld_bf16x8(&Kld[bf][(r0 * 8 + ((quad + 4) ^ (r0 & 7))) * 8]);
            f32x4 s = minit;
            s = __builtin_amdgcn_mfma_f32_16x16x32_bf16(ka0, qf0, s, 0, 0, 0);
            s = __builtin_amdgcn_mfma_f32_16x16x32_bf16(ka1, qf1, s, 0, 0, 0);
            float e0 = EXP2(s[0]), e1 = EXP2(s[1]);
            float e2 = EXP2(s[2]), e3 = EXP2(s[3]);
            ps += (e0 + e1) + (e2 + e3);
            *(uint2*)&tb[wave][lcol * 68 + kt * 16 + quad * 4] =
                make_uint2(pk2bf(e0, e1), pk2bf(e2, e3));
        }

        // PV: A = P (from tbuf, wave-private, DS in-order), B = V (from Vld)
        #pragma unroll
        for (int kf2 = 0; kf2 < 2; ++kf2) {
            bf16x8 pa = *(const bf16x8*)&tb[wave][lcol * 68 + kf2 * 32 + quad * 8];
            #pragma unroll
            for (int nt = 0; nt < 4; ++nt) {
                int dh = nt * 16 + lcol;
                bf16x8 vb = ld_bf16x8(&Vld[bf][(dh * 8 + ((kf2 * 4 + quad) ^ (dh & 7))) * 8]);
                oacc[nt] = __builtin_amdgcn_mfma_f32_16x16x32_bf16(pa, vb, oacc[nt], 0, 0, 0);
            }
        }
        __syncthreads();
    }

    // ---- epilogue: per-row normalize (rows owned entirely by this wave) ----
    ps += __shfl_xor(ps, 16, 64);
    ps += __shfl_xor(ps, 32, 64);
    float inv = 1.0f / ps;   // valid at lanes where lcol == q-row
    #pragma unroll
    for (int r = 0; r < 4; ++r) {
        float iv = __shfl(inv, quad * 4 + r, 64);
        int srow = rowbase + quad * 4 + r;
        size_t base = (((size_t)b * SS + srow) * HH + h) * DHD;
        #pragma unroll
        for (int nt = 0; nt < 4; ++nt)
            Ob[base + nt * 16 + lcol] = f2bf(oacc[nt][r] * iv);
    }
}

// ====================== output GEMM (64x128 tile, 512 blocks) ======================
__global__ __launch_bounds__(256) void out_gemm(
    const unsigned short* __restrict__ Ob,
    const unsigned short* __restrict__ Wto,
    const float* __restrict__ bo,
    float* __restrict__ out)
{
    __shared__ __align__(16) unsigned short Ald[2][64 * 32];
    __shared__ __align__(16) unsigned short Bld[2][128 * 32];

    const int m0g = blockIdx.y * 64;
    const int n0g = blockIdx.x * 128;
    const int wave = threadIdx.x >> 6, lane = threadIdx.x & 63;
    const int quad = lane >> 4, lcol = lane & 15;
    const int nb = wave * 32;

    f32x4 acc[4][2];
    #pragma unroll
    for (int i = 0; i < 4; ++i)
        #pragma unroll
        for (int j = 0; j < 2; ++j) acc[i][j] = (f32x4){0.f, 0.f, 0.f, 0.f};

    auto stage = [&](int ks, int bf) {
        #pragma unroll
        for (int i = 0; i < 3; ++i) {
            int j = wave * 3 + i;
            if (j < 4) { // A: Ob rows m0g..m0g+63
                int bi = j * 64 + lane;
                int row = bi >> 2, p = (bi & 3) ^ (row & 3);
                gl16(Ob + (size_t)(m0g + row) * DD + ks + p * 8, &Ald[bf][j * 512]);
            } else {     // B: Wto rows n0g..n0g+127
                int jj = j - 4;
                int bi = jj * 64 + lane;
                int row = bi >> 2, p = (bi & 3) ^ (row & 3);
                gl16(Wto + (size_t)(n0g + row) * DD + ks + p * 8, &Bld[bf][jj * 512]);
            }
        }
    };

    stage(0, 0);
    __syncthreads();

    for (int kk = 0; kk < 32; ++kk) {
        int bf = kk & 1;
        if (kk + 1 < 32) stage((kk + 1) * 32, (kk + 1) & 1);
        bf16x8 af[4], bfr[2];
        #pragma unroll
        for (int mt = 0; mt < 4; ++mt) {
            int row = mt * 16 + lcol;
            af[mt] = ld_bf16x8(&Ald[bf][(row * 4 + (quad ^ (row & 3))) * 8]);
        }
        #pragma unroll
        for (int nt = 0; nt < 2; ++nt) {
            int row = nb + nt * 16 + lcol;
            bfr[nt] = ld_bf16x8(&Bld[bf][(row * 4 + (quad ^ (row & 3))) * 8]);
        }
        #pragma unroll
        for (int mt = 0; mt < 4; ++mt)
            #pragma unroll
            for (int nt = 0; nt < 2; ++nt)
                acc[mt][nt] = __builtin_amdgcn_mfma_f32_16x16x32_bf16(af[mt], bfr[nt], acc[mt][nt], 0, 0, 0);
        __syncthreads();
    }

    #pragma unroll
    for (int mt = 0; mt < 4; ++mt)
        #pragma unroll
        for (int nt = 0; nt < 2; ++nt) {
            int n = n0g + nb + nt * 16 + lcol;
            float bv_ = bo[n];
            #pragma unroll
            for (int r = 0; r < 4; ++r) {
                int m = m0g + mt * 16 + quad * 4 + r;
                out[(size_t)m * DD + n] = acc[mt][nt][r] + bv_;
            }
        }
}

extern "C" void kernel_launch(void* const* d_in, const int* in_sizes, int n_in,
                              void* d_out, int out_size, void* d_ws, size_t ws_size,
                              hipStream_t stream)
{
    const float* x  = (const float*)d_in[0];
    const float* Wq = (const float*)d_in[1];
    const float* bq = (const float*)d_in[2];
    const float* Wk = (const float*)d_in[3];
    const float* bk = (const float*)d_in[4];
    const float* Wv = (const float*)d_in[5];
    const float* bv = (const float*)d_in[6];
    const float* Wo = (const float*)d_in[7];
    const float* bo = (const float*)d_in[8];
    float* out = (float*)d_out;

    unsigned short* ws = (unsigned short*)d_ws;
    unsigned short* Wt  = ws;                        // 4 * D*D (q,k,v,o)
    unsigned short* Wto = Wt + 3 * (size_t)DD * DD;
    unsigned short* Qb  = Wt + 4 * (size_t)DD * DD;  // M*D each
    unsigned short* Kb  = Qb + (size_t)MM * DD;
    unsigned short* Vt  = Kb + (size_t)MM * DD;
    unsigned short* xb  = Vt + (size_t)MM * DD;      // total 40 MB
    unsigned short* Ob  = xb;                        // alias: xb dead after qkv_gemm

    prep<<<8192, 256, 0, stream>>>(x, xb, Wq, Wk, Wv, Wo, Wt);

    qkv_gemm<<<dim3(DD / 128, MM / 128, 3), 256, 0, stream>>>(xb, Wt, bq, bk, bv, Qb, Kb, Vt);

    attn<<<dim3(16, 32), 512, 0, stream>>>(Qb, Kb, Vt, Ob);

    out_gemm<<<dim3(DD / 128, MM / 64), 256, 0, stream>>>(Ob, Wto, bo, out);
}